// Round 4
// baseline (784.161 us; speedup 1.0000x reference)
//
#include <hip/hip_runtime.h>
#include <hip/hip_bf16.h>
#include <stdint.h>

typedef __attribute__((ext_vector_type(8))) short short8;
typedef __attribute__((ext_vector_type(4))) float f32x4;

__device__ __forceinline__ f32x4 mfma16(short8 a, short8 b, f32x4 c) {
  return __builtin_amdgcn_mfma_f32_16x16x32_bf16(a, b, c, 0, 0, 0);
}

__device__ __forceinline__ ushort f2bf(float f) {
  __hip_bfloat16 h = __float2bfloat16(f);
  return __builtin_bit_cast(ushort, h);
}

// load 8 consecutive f32 and convert to a bf16 fragment
__device__ __forceinline__ short8 cvt8(const float* p) {
  float4 a = *(const float4*)p;
  float4 b = *(const float4*)(p + 4);
  short8 r;
  r[0] = (short)f2bf(a.x); r[1] = (short)f2bf(a.y);
  r[2] = (short)f2bf(a.z); r[3] = (short)f2bf(a.w);
  r[4] = (short)f2bf(b.x); r[5] = (short)f2bf(b.y);
  r[6] = (short)f2bf(b.z); r[7] = (short)f2bf(b.w);
  return r;
}

// async global->LDS, 16B per lane. LDS dest = wave-uniform base + lane*16.
typedef const __attribute__((address_space(1))) void* gvp;
typedef __attribute__((address_space(3))) void* lvp;
__device__ __forceinline__ void gl_lds16(const void* g, void* l) {
  __builtin_amdgcn_global_load_lds((gvp)g, (lvp)l, 16, 0, 0);
}

// XOR-8 swizzle on 16B-chunk index: LDS chunk l holds global chunk swz(l).
// Involution within each 8-chunk (128B) row; row = l>>3 preserved.
__device__ __forceinline__ int swz(int l) {
  return (l & ~7) | ((l & 7) ^ ((l >> 3) & 7));
}

// ---------------- pre-convert: f32 -> bf16 ----------------
struct CvtArgs { const float* src; ushort* dst; int n4; };
struct CvtArgs7 { CvtArgs a[7]; };

__global__ __launch_bounds__(256) void convert_kernel(CvtArgs7 ca) {
  CvtArgs c = ca.a[blockIdx.y];
  for (int i = blockIdx.x * 256 + threadIdx.x; i < c.n4; i += gridDim.x * 256) {
    float4 f = ((const float4*)c.src)[i];
    uint2 o;
    o.x = (uint)f2bf(f.x) | ((uint)f2bf(f.y) << 16);
    o.y = (uint)f2bf(f.z) | ((uint)f2bf(f.w) << 16);
    *(uint2*)(c.dst + (size_t)i * 4) = o;
  }
}

// ---------------- projections ----------------
struct ProjArgs {
  const ushort* x;      // bf16 activations [8192,512]
  const void* w;        // weights [512,512]: bf16 (wf=0) or f32 (wf=1)
  const float* b;       // bias f32
  void* out;            // bf16 ws (mode 0/1) or f32 d_out (mode 2)
  float scale; int mode; int wf;
};
struct ProjArgs3 { ProjArgs p[3]; };

// out[row,col] = (sum_k x[row,k]*w[col,k] + b[col]) * scale
// M=8192,N=512,K=512. Tile 128x64, 4 waves, BK=32, global_load_lds staging.
__global__ __launch_bounds__(256) void proj_kernel(ProjArgs3 pa3) {
  ProjArgs pa = pa3.p[blockIdx.z];
  const int tid = threadIdx.x;
  const int wave = tid >> 6, lane = tid & 63;
  const int qd = lane >> 4, n = lane & 15;
  const int rowbase = blockIdx.x * 128;
  const int colbase = blockIdx.y * 64;

  __shared__ __attribute__((aligned(16))) ushort smem[10240];  // 20KB
  ushort* As = smem;          // [128][32]
  ushort* Bs = smem + 4096;   // [64][32]

  const int brow = tid >> 2, bchk = tid & 3;
  const int ldsw = (tid & ~63) * 8;  // wave-uniform chunk base (ushorts)

  const f32x4 fzero = {0.f, 0.f, 0.f, 0.f};
  f32x4 acc[2][4];
#pragma unroll
  for (int r = 0; r < 2; r++)
#pragma unroll
    for (int j = 0; j < 4; j++) acc[r][j] = fzero;

  for (int k0 = 0; k0 < 512; k0 += 32) {
    gl_lds16(pa.x + (size_t)(rowbase + brow) * 512 + k0 + bchk * 8, As + ldsw);
    gl_lds16(pa.x + (size_t)(rowbase + 64 + brow) * 512 + k0 + bchk * 8,
             As + 2048 + ldsw);
    if (pa.wf) {
      short8 bv = cvt8((const float*)pa.w + (size_t)(colbase + brow) * 512 + k0 + bchk * 8);
      *(short8*)&Bs[(size_t)tid * 8] = bv;
    } else {
      gl_lds16((const ushort*)pa.w + (size_t)(colbase + brow) * 512 + k0 + bchk * 8,
               Bs + ldsw);
    }
    __syncthreads();  // drains vmcnt (async LDS writes) + lgkm

    short8 a0 = *(const short8*)&As[(wave * 32 + n) * 32 + qd * 8];
    short8 a1 = *(const short8*)&As[(wave * 32 + 16 + n) * 32 + qd * 8];
#pragma unroll
    for (int j = 0; j < 4; j++) {
      short8 bf = *(const short8*)&Bs[(j * 16 + n) * 32 + qd * 8];
      acc[0][j] = mfma16(a0, bf, acc[0][j]);
      acc[1][j] = mfma16(a1, bf, acc[1][j]);
    }
    __syncthreads();  // reads done before next iter's writes
  }

  const int wrow = rowbase + wave * 32;

  if (pa.mode == 1) {
    // transpose epilogue: [col][row] stage in LDS, coalesced rows of vpT
    ushort* tb = smem + wave * 2560;  // [64][40]
#pragma unroll
    for (int r = 0; r < 2; r++)
#pragma unroll
      for (int j = 0; j < 4; j++)
#pragma unroll
        for (int i = 0; i < 4; i++) {
          int ol = j * 16 + n;
          int ll = r * 16 + qd * 4 + i;
          float vv = (acc[r][j][i] + pa.b[colbase + ol]) * pa.scale;
          tb[ol * 40 + ll] = f2bf(vv);
        }
    int o = colbase + lane;
    int h2 = o >> 6, dd = o & 63;
    int bb2 = wrow >> 11, l0 = wrow & 2047;
    size_t base = ((size_t)((bb2 * 8 + h2) * 64 + dd)) * 2048 + l0;
    ushort* ob = (ushort*)pa.out;
#pragma unroll
    for (int c = 0; c < 4; c++) {
      uint4 vdata = *(const uint4*)(tb + lane * 40 + c * 8);
      *(uint4*)(ob + base + c * 8) = vdata;
    }
  } else {
#pragma unroll
    for (int r = 0; r < 2; r++)
#pragma unroll
      for (int j = 0; j < 4; j++)
#pragma unroll
        for (int i = 0; i < 4; i++) {
          int col = colbase + j * 16 + n;
          int row = wrow + r * 16 + qd * 4 + i;
          float vv = (acc[r][j][i] + pa.b[col]) * pa.scale;
          if (pa.mode == 0) {
            int bb2 = row >> 11, l = row & 2047, h2 = col >> 6, dd = col & 63;
            ((ushort*)pa.out)[((size_t)((bb2 * 8 + h2) * 2048 + l)) * 64 + dd] = f2bf(vv);
          } else {
            ((float*)pa.out)[(size_t)row * 512 + col] = vv;
          }
        }
  }
}

// ---------------- attention ----------------
// Block = 4 waves = 64 q rows (wave w: q0 = qt*64 + w*16), FULL k range.
// BK=64: K tile 8KB (+V tile 8KB in pass 2) double-buffered via
// global_load_lds, shared by all 4 waves. K AND V XOR-8 swizzled at the
// SOURCE (linear LDS dest); both tiles have 128B rows so the swizzle makes
// every frag ds_read_b128 an 8-lane same-address broadcast (conflict-free).
// Half the barriers of BK=32. attn stores are plain (NOT nontemporal) so the
// four 64B t-segments per row aggregate into full L2 lines before writeback.
// Swapped-operand QK^T: lane (qd,n) holds S[k=kk+qd*4+i][q=q0+n].
__global__ __launch_bounds__(256, 3) void attn_kernel(
    const ushort* __restrict__ qp, const ushort* __restrict__ kp,
    const ushort* __restrict__ vpT, const int* __restrict__ mask,
    float* __restrict__ attn, ushort* __restrict__ ao) {
  const int bb = blockIdx.z, h = blockIdx.y, qt = blockIdx.x;
  const int tid = threadIdx.x;
  const int wave = tid >> 6, lane = tid & 63;
  const int qd = lane >> 4, n = lane & 15;

  __shared__ __attribute__((aligned(16))) float maskb[2048];      // 8KB
  __shared__ __attribute__((aligned(16))) ushort Kb[2][4096];     // 2x8KB
  __shared__ __attribute__((aligned(16))) ushort Vb[2][4096];     // 2x8KB
  __shared__ __attribute__((aligned(16))) ushort pbuf[4][16 * 80];// 10KB

  {
    int i = tid * 8;
    const int* mp = mask + bb * 2048 + i;
    int4 m0 = *(const int4*)mp;
    int4 m1 = *(const int4*)(mp + 4);
    *(float4*)&maskb[i] =
        make_float4(-1e9f * m0.x, -1e9f * m0.y, -1e9f * m0.z, -1e9f * m0.w);
    *(float4*)&maskb[i + 4] =
        make_float4(-1e9f * m1.x, -1e9f * m1.y, -1e9f * m1.z, -1e9f * m1.w);
  }

  const size_t bh = (size_t)(bb * 8 + h);
  const ushort* qph = qp + bh * (2048 * 64);
  const ushort* kph = kp + bh * (2048 * 64);
  const ushort* vph = vpT + bh * (64 * 2048);

  const int q0 = qt * 64 + wave * 16;
  short8 qf0 = *(const short8*)(qph + (size_t)(q0 + n) * 64 + qd * 8);
  short8 qf1 = *(const short8*)(qph + (size_t)(q0 + n) * 64 + 32 + qd * 8);

  // staging constants: 256 threads cover an 8KB (512-chunk) tile in 2 calls.
  const int kgA = swz(tid), kgB = swz(tid + 256);
  const int vrA = tid >> 3, vcA = (tid & 7) ^ (vrA & 7);
  const int vrB = vrA + 32;  // (vrB & 7) == (vrA & 7) -> same chunk xor
  const int ucb = (tid & ~63) * 8;  // wave-uniform LDS ushort base, call A

  // frag read byte offset within a [64 rows][128B] swizzled tile:
  // row r, 16B chunk c -> r*128 + ((c ^ (r&7))<<4); chunk c+4 == ^64.
  const int ka = n * 128 + (((qd ^ (n & 7)) & 7) << 4);

  const f32x4 fzero = {0.f, 0.f, 0.f, 0.f};

  // ---- pass 1: denominators (no max subtraction: |scores| ~ 2, safe)
  gl_lds16(kph + (size_t)kgA * 8, (ushort*)Kb[0] + ucb);
  gl_lds16(kph + (size_t)kgB * 8, (ushort*)Kb[0] + 2048 + ucb);
  __syncthreads();
  float lsum = 0.f;
  int buf = 0;
  for (int k0 = 0; k0 < 2048; k0 += 64) {
    if (k0 + 64 < 2048) {
      gl_lds16(kph + (size_t)(k0 + 64) * 64 + (size_t)kgA * 8,
               (ushort*)Kb[buf ^ 1] + ucb);
      gl_lds16(kph + (size_t)(k0 + 64) * 64 + (size_t)kgB * 8,
               (ushort*)Kb[buf ^ 1] + 2048 + ucb);
    }
    const char* KB = (const char*)Kb[buf];
#pragma unroll
    for (int t = 0; t < 4; t++) {
      int kao = ka + t * 2048;
      short8 kf0 = *(const short8*)(KB + kao);
      short8 kf1 = *(const short8*)(KB + (kao ^ 64));
      f32x4 s = mfma16(kf0, qf0, fzero);
      s = mfma16(kf1, qf1, s);
      f32x4 mv = *(const f32x4*)&maskb[k0 + t * 16 + qd * 4];
      float e0 = __expf(s[0] + mv[0]);
      float e1 = __expf(s[1] + mv[1]);
      float e2 = __expf(s[2] + mv[2]);
      float e3 = __expf(s[3] + mv[3]);
      lsum += (e0 + e1) + (e2 + e3);
    }
    __syncthreads();
    buf ^= 1;
  }
  lsum += __shfl_xor(lsum, 16, 64);
  lsum += __shfl_xor(lsum, 32, 64);
  float inv = 1.0f / fmaxf(lsum, 1e-30f);

  // ---- pass 2: normalized attn writes (float4, L2-aggregated) + PV
  f32x4 oacc[4];
#pragma unroll
  for (int j = 0; j < 4; j++) oacc[j] = fzero;

  ushort* pb = pbuf[wave];
  float* arow = attn + (bh * 2048 + (size_t)(q0 + n)) * 2048 + qd * 4;

  gl_lds16(kph + (size_t)kgA * 8, (ushort*)Kb[0] + ucb);
  gl_lds16(kph + (size_t)kgB * 8, (ushort*)Kb[0] + 2048 + ucb);
  gl_lds16(vph + (size_t)vrA * 2048 + vcA * 8, (ushort*)Vb[0] + ucb);
  gl_lds16(vph + (size_t)vrB * 2048 + vcA * 8, (ushort*)Vb[0] + 2048 + ucb);
  __syncthreads();
  buf = 0;
  for (int k0 = 0; k0 < 2048; k0 += 64) {
    if (k0 + 64 < 2048) {
      gl_lds16(kph + (size_t)(k0 + 64) * 64 + (size_t)kgA * 8,
               (ushort*)Kb[buf ^ 1] + ucb);
      gl_lds16(kph + (size_t)(k0 + 64) * 64 + (size_t)kgB * 8,
               (ushort*)Kb[buf ^ 1] + 2048 + ucb);
      gl_lds16(vph + (size_t)vrA * 2048 + (k0 + 64) + vcA * 8,
               (ushort*)Vb[buf ^ 1] + ucb);
      gl_lds16(vph + (size_t)vrB * 2048 + (k0 + 64) + vcA * 8,
               (ushort*)Vb[buf ^ 1] + 2048 + ucb);
    }
    const char* KB = (const char*)Kb[buf];
    const char* VB = (const char*)Vb[buf];
#pragma unroll
    for (int t = 0; t < 4; t++) {
      int kao = ka + t * 2048;
      short8 kf0 = *(const short8*)(KB + kao);
      short8 kf1 = *(const short8*)(KB + (kao ^ 64));
      f32x4 s = mfma16(kf0, qf0, fzero);
      s = mfma16(kf1, qf1, s);
      f32x4 mv = *(const f32x4*)&maskb[k0 + t * 16 + qd * 4];
      f32x4 p;
      p[0] = __expf(s[0] + mv[0]) * inv;
      p[1] = __expf(s[1] + mv[1]) * inv;
      p[2] = __expf(s[2] + mv[2]) * inv;
      p[3] = __expf(s[3] + mv[3]) * inv;
      *(f32x4*)(arow + k0 + t * 16) = p;  // plain store: L2 line aggregation
      uint2 pk2;
      pk2.x = (uint)f2bf(p[0]) | ((uint)f2bf(p[1]) << 16);
      pk2.y = (uint)f2bf(p[2]) | ((uint)f2bf(p[3]) << 16);
      *(uint2*)(pb + n * 80 + t * 16 + qd * 4) = pk2;  // P[q=n][k] bf16
    }
    // wave-private LDS: lgkmcnt orders writes -> these reads
    short8 af0 = *(const short8*)(pb + n * 80 + qd * 8);       // k 0..31
    short8 af1 = *(const short8*)(pb + n * 80 + 32 + qd * 8);  // k 32..63
#pragma unroll
    for (int j = 0; j < 4; j++) {
      int vao = ka + j * 2048;  // row j*16+n, chunk qd (swizzled)
      short8 vf0 = *(const short8*)(VB + vao);
      short8 vf1 = *(const short8*)(VB + (vao ^ 64));
      oacc[j] = mfma16(af0, vf0, oacc[j]);
      oacc[j] = mfma16(af1, vf1, oacc[j]);
    }
    __syncthreads();
    buf ^= 1;
  }

  // epilogue: concat-head layout [B*L, 512], bf16 ws (wave owns full k)
#pragma unroll
  for (int j = 0; j < 4; j++)
#pragma unroll
    for (int i = 0; i < 4; i++) {
      int rowg = q0 + qd * 4 + i;
      int col = h * 64 + j * 16 + n;
      ao[(size_t)(bb * 2048 + rowg) * 512 + col] = f2bf(oacc[j][i]);
    }
}

extern "C" void kernel_launch(void* const* d_in, const int* in_sizes, int n_in,
                              void* d_out, int out_size, void* d_ws, size_t ws_size,
                              hipStream_t stream) {
  (void)in_sizes; (void)n_in; (void)out_size;
  const float* q = (const float*)d_in[0];
  const float* k = (const float*)d_in[1];
  const float* v = (const float*)d_in[2];
  const int* mask = (const int*)d_in[3];

  float* out = (float*)d_out;
  float* attn = out + (size_t)4 * 2048 * 512;

  ushort* qp = (ushort*)d_ws;
  ushort* kp = qp + 4194304;
  ushort* vpT = kp + 4194304;
  ushort* ao = vpT + 4194304;
  // wo bf16 lives in d_ws after ao (must survive attn_kernel) if room
  ushort* wob = ao + 4194304;
  const bool wo_ws = ws_size >= 34078720;  // 32MB + 512KB

  // bf16 conversion scratch carved from the tail of the attn output buffer:
  // read only by proj1, overwritten later by attn_kernel. 480MB..505.5MB.
  char* attnB = (char*)attn;
  ushort* xq = (ushort*)(attnB + 503316480);
  ushort* xk = xq + 4194304;
  ushort* xv = xk + 4194304;
  ushort* wqb = xv + 4194304;
  ushort* wkb = wqb + 262144;
  ushort* wvb = wkb + 262144;

  CvtArgs7 cv;
  cv.a[0] = { q, xq, 1048576 };
  cv.a[1] = { k, xk, 1048576 };
  cv.a[2] = { v, xv, 1048576 };
  cv.a[3] = { (const float*)d_in[4], wqb, 65536 };
  cv.a[4] = { (const float*)d_in[6], wkb, 65536 };
  cv.a[5] = { (const float*)d_in[8], wvb, 65536 };
  cv.a[6] = { (const float*)d_in[10], wob, wo_ws ? 65536 : 0 };
  convert_kernel<<<dim3(256, 7), 256, 0, stream>>>(cv);

  ProjArgs3 pa;
  pa.p[0] = { xq, wqb, (const float*)d_in[5], qp,  0.125f, 0, 0 };
  pa.p[1] = { xk, wkb, (const float*)d_in[7], kp,  1.0f,   0, 0 };
  pa.p[2] = { xv, wvb, (const float*)d_in[9], vpT, 1.0f,   1, 0 };
  proj_kernel<<<dim3(64, 8, 3), 256, 0, stream>>>(pa);

  attn_kernel<<<dim3(32, 8, 4), 256, 0, stream>>>(qp, kp, vpT, mask, attn, ao);

  ProjArgs3 po;
  po.p[0] = { ao, wo_ws ? (const void*)wob : (const void*)d_in[10],
              (const float*)d_in[11], out, 1.0f, 2, wo_ws ? 0 : 1 };
  po.p[1] = po.p[0]; po.p[2] = po.p[0];
  proj_kernel<<<dim3(64, 8, 1), 256, 0, stream>>>(po);
}

// Round 5
// 744.949 us; speedup vs baseline: 1.0526x; 1.0526x over previous
//
#include <hip/hip_runtime.h>
#include <hip/hip_bf16.h>
#include <stdint.h>

typedef __attribute__((ext_vector_type(8))) short short8;
typedef __attribute__((ext_vector_type(4))) float f32x4;

__device__ __forceinline__ f32x4 mfma16(short8 a, short8 b, f32x4 c) {
  return __builtin_amdgcn_mfma_f32_16x16x32_bf16(a, b, c, 0, 0, 0);
}

__device__ __forceinline__ ushort f2bf(float f) {
  __hip_bfloat16 h = __float2bfloat16(f);
  return __builtin_bit_cast(ushort, h);
}

// load 8 consecutive f32 and convert to a bf16 fragment
__device__ __forceinline__ short8 cvt8(const float* p) {
  float4 a = *(const float4*)p;
  float4 b = *(const float4*)(p + 4);
  short8 r;
  r[0] = (short)f2bf(a.x); r[1] = (short)f2bf(a.y);
  r[2] = (short)f2bf(a.z); r[3] = (short)f2bf(a.w);
  r[4] = (short)f2bf(b.x); r[5] = (short)f2bf(b.y);
  r[6] = (short)f2bf(b.z); r[7] = (short)f2bf(b.w);
  return r;
}

// async global->LDS, 16B per lane. LDS dest = wave-uniform base + lane*16.
typedef const __attribute__((address_space(1))) void* gvp;
typedef __attribute__((address_space(3))) void* lvp;
__device__ __forceinline__ void gl_lds16(const void* g, void* l) {
  __builtin_amdgcn_global_load_lds((gvp)g, (lvp)l, 16, 0, 0);
}

// XOR-8 swizzle on 16B-chunk index: LDS chunk l holds global chunk swz(l).
// Involution within each 8-chunk (128B) group; group = l>>3 preserved.
__device__ __forceinline__ int swz(int l) {
  return (l & ~7) | ((l & 7) ^ ((l >> 3) & 7));
}

// ---------------- pre-convert: f32 -> bf16 ----------------
struct CvtArgs { const float* src; ushort* dst; int n4; };
struct CvtArgs7 { CvtArgs a[7]; };

__global__ __launch_bounds__(256) void convert_kernel(CvtArgs7 ca) {
  CvtArgs c = ca.a[blockIdx.y];
  for (int i = blockIdx.x * 256 + threadIdx.x; i < c.n4; i += gridDim.x * 256) {
    float4 f = ((const float4*)c.src)[i];
    uint2 o;
    o.x = (uint)f2bf(f.x) | ((uint)f2bf(f.y) << 16);
    o.y = (uint)f2bf(f.z) | ((uint)f2bf(f.w) << 16);
    *(uint2*)(c.dst + (size_t)i * 4) = o;
  }
}

// ---------------- projections ----------------
struct ProjArgs {
  const ushort* x;      // bf16 activations [8192,512]
  const void* w;        // weights [512,512]: bf16 (wf=0) or f32 (wf=1)
  const float* b;       // bias f32
  void* out;            // bf16 ws (mode 0/1) or f32 d_out (mode 2)
  float scale; int mode; int wf;
};
struct ProjArgs3 { ProjArgs p[3]; };

// out[row,col] = (sum_k x[row,k]*w[col,k] + b[col]) * scale
// M=8192,N=512,K=512. Tile 128x64, 4 waves, BK=32, global_load_lds staging.
__global__ __launch_bounds__(256) void proj_kernel(ProjArgs3 pa3) {
  ProjArgs pa = pa3.p[blockIdx.z];
  const int tid = threadIdx.x;
  const int wave = tid >> 6, lane = tid & 63;
  const int qd = lane >> 4, n = lane & 15;
  const int rowbase = blockIdx.x * 128;
  const int colbase = blockIdx.y * 64;

  __shared__ __attribute__((aligned(16))) ushort smem[10240];  // 20KB
  ushort* As = smem;          // [128][32]
  ushort* Bs = smem + 4096;   // [64][32]

  const int brow = tid >> 2, bchk = tid & 3;
  const int ldsw = (tid & ~63) * 8;  // wave-uniform chunk base (ushorts)

  const f32x4 fzero = {0.f, 0.f, 0.f, 0.f};
  f32x4 acc[2][4];
#pragma unroll
  for (int r = 0; r < 2; r++)
#pragma unroll
    for (int j = 0; j < 4; j++) acc[r][j] = fzero;

  for (int k0 = 0; k0 < 512; k0 += 32) {
    gl_lds16(pa.x + (size_t)(rowbase + brow) * 512 + k0 + bchk * 8, As + ldsw);
    gl_lds16(pa.x + (size_t)(rowbase + 64 + brow) * 512 + k0 + bchk * 8,
             As + 2048 + ldsw);
    if (pa.wf) {
      short8 bv = cvt8((const float*)pa.w + (size_t)(colbase + brow) * 512 + k0 + bchk * 8);
      *(short8*)&Bs[(size_t)tid * 8] = bv;
    } else {
      gl_lds16((const ushort*)pa.w + (size_t)(colbase + brow) * 512 + k0 + bchk * 8,
               Bs + ldsw);
    }
    __syncthreads();  // drains vmcnt (async LDS writes) + lgkm

    short8 a0 = *(const short8*)&As[(wave * 32 + n) * 32 + qd * 8];
    short8 a1 = *(const short8*)&As[(wave * 32 + 16 + n) * 32 + qd * 8];
#pragma unroll
    for (int j = 0; j < 4; j++) {
      short8 bf = *(const short8*)&Bs[(j * 16 + n) * 32 + qd * 8];
      acc[0][j] = mfma16(a0, bf, acc[0][j]);
      acc[1][j] = mfma16(a1, bf, acc[1][j]);
    }
    __syncthreads();  // reads done before next iter's writes
  }

  const int wrow = rowbase + wave * 32;

  if (pa.mode == 1) {
    // transpose epilogue: [col][row] stage in LDS, coalesced rows of vpT
    ushort* tb = smem + wave * 2560;  // [64][40]
#pragma unroll
    for (int r = 0; r < 2; r++)
#pragma unroll
      for (int j = 0; j < 4; j++)
#pragma unroll
        for (int i = 0; i < 4; i++) {
          int ol = j * 16 + n;
          int ll = r * 16 + qd * 4 + i;
          float vv = (acc[r][j][i] + pa.b[colbase + ol]) * pa.scale;
          tb[ol * 40 + ll] = f2bf(vv);
        }
    int o = colbase + lane;
    int h2 = o >> 6, dd = o & 63;
    int bb2 = wrow >> 11, l0 = wrow & 2047;
    size_t base = ((size_t)((bb2 * 8 + h2) * 64 + dd)) * 2048 + l0;
    ushort* ob = (ushort*)pa.out;
#pragma unroll
    for (int c = 0; c < 4; c++) {
      uint4 vdata = *(const uint4*)(tb + lane * 40 + c * 8);
      *(uint4*)(ob + base + c * 8) = vdata;
    }
  } else {
#pragma unroll
    for (int r = 0; r < 2; r++)
#pragma unroll
      for (int j = 0; j < 4; j++)
#pragma unroll
        for (int i = 0; i < 4; i++) {
          int col = colbase + j * 16 + n;
          int row = wrow + r * 16 + qd * 4 + i;
          float vv = (acc[r][j][i] + pa.b[col]) * pa.scale;
          if (pa.mode == 0) {
            int bb2 = row >> 11, l = row & 2047, h2 = col >> 6, dd = col & 63;
            ((ushort*)pa.out)[((size_t)((bb2 * 8 + h2) * 2048 + l)) * 64 + dd] = f2bf(vv);
          } else {
            ((float*)pa.out)[(size_t)row * 512 + col] = vv;
          }
        }
  }
}

// ---------------- attention ----------------
// Block = 4 waves = 64 q rows (wave w: q0 = qt*64 + w*16), FULL k range.
// BK=32: K tile 4KB [32k][128B rows], V tile 4KB [64d][64B rows], both
// double-buffered via global_load_lds and shared by all 4 waves.
// LDS = 21KB -> 7 blocks/CU (28 waves/CU), the latency-hiding lever.
// K swizzle: XOR-8 within 128B rows (conflict-free reads).
// V swizzle: XOR-8 over the FLAT tile (128B groups span row pairs); read
// banks = ((n&1)*4+qd)^(n>>1) -> every bank hit exactly 2x = free (m136).
// Mask read from global (L2-resident, 16-lane shared addr) - no maskb LDS.
// XCD swizzle: block i runs on XCD i%8; sid gives XCD j a contiguous range
// covering 4 whole (bb,h) K/V panels (2MB) -> L2-local, kills over-fetch.
// Swapped-operand QK^T: lane (qd,n) holds S[k=kk+qd*4+i][q=q0+n].
__global__ __launch_bounds__(256, 7) void attn_kernel(
    const ushort* __restrict__ qp, const ushort* __restrict__ kp,
    const ushort* __restrict__ vpT, const int* __restrict__ mask,
    float* __restrict__ attn, ushort* __restrict__ ao) {
  const int tid = threadIdx.x;
  const int wave = tid >> 6, lane = tid & 63;
  const int qd = lane >> 4, n = lane & 15;
  const int sid = (blockIdx.x & 7) * 128 + (blockIdx.x >> 3);
  const int qt = sid & 31, h = (sid >> 5) & 7, bb = sid >> 8;

  __shared__ __attribute__((aligned(16))) ushort Kb[2][2048];      // 2x4KB
  __shared__ __attribute__((aligned(16))) ushort Vb[2][2048];      // 2x4KB
  __shared__ __attribute__((aligned(16))) ushort pbuf[4][16 * 40]; // 5KB

  const size_t bh = (size_t)(bb * 8 + h);
  const ushort* qph = qp + bh * (2048 * 64);
  const ushort* kph = kp + bh * (2048 * 64);
  const ushort* vph = vpT + bh * (64 * 2048);
  const int* mrow = mask + bb * 2048 + qd * 4;

  const int q0 = qt * 64 + wave * 16;
  short8 qf0 = *(const short8*)(qph + (size_t)(q0 + n) * 64 + qd * 8);
  short8 qf1 = *(const short8*)(qph + (size_t)(q0 + n) * 64 + 32 + qd * 8);

  // staging: LDS chunk tid holds global chunk swz(tid); 256 chunks = 4KB
  const int kg = swz(tid);                       // K: linear in tile
  const int vrow = swz(tid) >> 2;                // V: row stride 2048
  const int vko = (swz(tid) & 3) * 8;
  const int ucb = (tid & ~63) * 8;               // wave-uniform ushort base

  // K frag read: row t*16+n (128B), chunk c=qd (kf0) / qd+4 (kf1 = ^64)
  const int ka = n * 128 + ((qd ^ (n & 7)) << 4);
  // V frag read: flat chunk c=j*64+n*4+qd -> swizzled byte offset
  const int vbase = (n >> 1) * 128 + ((((n & 1) * 4 + qd) ^ (n >> 1)) << 4);

  const f32x4 fzero = {0.f, 0.f, 0.f, 0.f};

  // ---- pass 1: denominators (no max subtraction: |scores| ~ 2, safe)
  gl_lds16(kph + (size_t)kg * 8, (ushort*)Kb[0] + ucb);
  __syncthreads();
  float lsum = 0.f;
  int buf = 0;
  for (int k0 = 0; k0 < 2048; k0 += 32) {
    if (k0 + 32 < 2048)
      gl_lds16(kph + (size_t)(k0 + 32) * 64 + (size_t)kg * 8,
               (ushort*)Kb[buf ^ 1] + ucb);
    const char* KB = (const char*)Kb[buf];
#pragma unroll
    for (int t = 0; t < 2; t++) {
      int kao = ka + t * 2048;
      short8 kf0 = *(const short8*)(KB + kao);
      short8 kf1 = *(const short8*)(KB + (kao ^ 64));
      f32x4 s = mfma16(kf0, qf0, fzero);
      s = mfma16(kf1, qf1, s);
      int4 mi = *(const int4*)(mrow + k0 + t * 16);
      float e0 = __expf(fmaf((float)mi.x, -1e9f, s[0]));
      float e1 = __expf(fmaf((float)mi.y, -1e9f, s[1]));
      float e2 = __expf(fmaf((float)mi.z, -1e9f, s[2]));
      float e3 = __expf(fmaf((float)mi.w, -1e9f, s[3]));
      lsum += (e0 + e1) + (e2 + e3);
    }
    __syncthreads();
    buf ^= 1;
  }
  lsum += __shfl_xor(lsum, 16, 64);
  lsum += __shfl_xor(lsum, 32, 64);
  float inv = 1.0f / fmaxf(lsum, 1e-30f);

  // ---- pass 2: normalized attn writes (float4, nontemporal) + PV
  f32x4 oacc[4];
#pragma unroll
  for (int j = 0; j < 4; j++) oacc[j] = fzero;

  ushort* pb = pbuf[wave];
  float* arow = attn + (bh * 2048 + (size_t)(q0 + n)) * 2048 + qd * 4;

  gl_lds16(kph + (size_t)kg * 8, (ushort*)Kb[0] + ucb);
  gl_lds16(vph + (size_t)vrow * 2048 + vko, (ushort*)Vb[0] + ucb);
  __syncthreads();
  buf = 0;
  for (int k0 = 0; k0 < 2048; k0 += 32) {
    if (k0 + 32 < 2048) {
      gl_lds16(kph + (size_t)(k0 + 32) * 64 + (size_t)kg * 8,
               (ushort*)Kb[buf ^ 1] + ucb);
      gl_lds16(vph + (size_t)vrow * 2048 + (k0 + 32) + vko,
               (ushort*)Vb[buf ^ 1] + ucb);
    }
    const char* KB = (const char*)Kb[buf];
    const char* VB = (const char*)Vb[buf];
#pragma unroll
    for (int t = 0; t < 2; t++) {
      int kao = ka + t * 2048;
      short8 kf0 = *(const short8*)(KB + kao);
      short8 kf1 = *(const short8*)(KB + (kao ^ 64));
      f32x4 s = mfma16(kf0, qf0, fzero);
      s = mfma16(kf1, qf1, s);
      int4 mi = *(const int4*)(mrow + k0 + t * 16);
      f32x4 p;
      p[0] = __expf(fmaf((float)mi.x, -1e9f, s[0])) * inv;
      p[1] = __expf(fmaf((float)mi.y, -1e9f, s[1])) * inv;
      p[2] = __expf(fmaf((float)mi.z, -1e9f, s[2])) * inv;
      p[3] = __expf(fmaf((float)mi.w, -1e9f, s[3])) * inv;
      __builtin_nontemporal_store(p, (f32x4*)(arow + k0 + t * 16));
      uint2 pk2;
      pk2.x = (uint)f2bf(p[0]) | ((uint)f2bf(p[1]) << 16);
      pk2.y = (uint)f2bf(p[2]) | ((uint)f2bf(p[3]) << 16);
      *(uint2*)(pb + n * 40 + t * 16 + qd * 4) = pk2;  // P[q=n][k] bf16
    }
    // wave-private LDS: lgkmcnt orders writes -> these reads
    short8 af = *(const short8*)(pb + n * 40 + qd * 8);  // A[m=n][k=qd*8+j]
#pragma unroll
    for (int j = 0; j < 4; j++) {
      short8 vf = *(const short8*)(VB + vbase + j * 1024);
      oacc[j] = mfma16(af, vf, oacc[j]);
    }
    __syncthreads();
    buf ^= 1;
  }

  // epilogue: concat-head layout [B*L, 512], bf16 ws (wave owns full k)
#pragma unroll
  for (int j = 0; j < 4; j++)
#pragma unroll
    for (int i = 0; i < 4; i++) {
      int rowg = q0 + qd * 4 + i;
      int col = h * 64 + j * 16 + n;
      ao[(size_t)(bb * 2048 + rowg) * 512 + col] = f2bf(oacc[j][i]);
    }
}

extern "C" void kernel_launch(void* const* d_in, const int* in_sizes, int n_in,
                              void* d_out, int out_size, void* d_ws, size_t ws_size,
                              hipStream_t stream) {
  (void)in_sizes; (void)n_in; (void)out_size;
  const float* q = (const float*)d_in[0];
  const float* k = (const float*)d_in[1];
  const float* v = (const float*)d_in[2];
  const int* mask = (const int*)d_in[3];

  float* out = (float*)d_out;
  float* attn = out + (size_t)4 * 2048 * 512;

  ushort* qp = (ushort*)d_ws;
  ushort* kp = qp + 4194304;
  ushort* vpT = kp + 4194304;
  ushort* ao = vpT + 4194304;
  // wo bf16 lives in d_ws after ao (must survive attn_kernel) if room
  ushort* wob = ao + 4194304;
  const bool wo_ws = ws_size >= 34078720;  // 32MB + 512KB

  // bf16 conversion scratch carved from the tail of the attn output buffer:
  // read only by proj1, overwritten later by attn_kernel. 480MB..505.5MB.
  char* attnB = (char*)attn;
  ushort* xq = (ushort*)(attnB + 503316480);
  ushort* xk = xq + 4194304;
  ushort* xv = xk + 4194304;
  ushort* wqb = xv + 4194304;
  ushort* wkb = wqb + 262144;
  ushort* wvb = wkb + 262144;

  CvtArgs7 cv;
  cv.a[0] = { q, xq, 1048576 };
  cv.a[1] = { k, xk, 1048576 };
  cv.a[2] = { v, xv, 1048576 };
  cv.a[3] = { (const float*)d_in[4], wqb, 65536 };
  cv.a[4] = { (const float*)d_in[6], wkb, 65536 };
  cv.a[5] = { (const float*)d_in[8], wvb, 65536 };
  cv.a[6] = { (const float*)d_in[10], wob, wo_ws ? 65536 : 0 };
  convert_kernel<<<dim3(256, 7), 256, 0, stream>>>(cv);

  ProjArgs3 pa;
  pa.p[0] = { xq, wqb, (const float*)d_in[5], qp,  0.125f, 0, 0 };
  pa.p[1] = { xk, wkb, (const float*)d_in[7], kp,  1.0f,   0, 0 };
  pa.p[2] = { xv, wvb, (const float*)d_in[9], vpT, 1.0f,   1, 0 };
  proj_kernel<<<dim3(64, 8, 3), 256, 0, stream>>>(pa);

  attn_kernel<<<dim3(1024, 1, 1), 256, 0, stream>>>(qp, kp, vpT, mask, attn, ao);

  ProjArgs3 po;
  po.p[0] = { ao, wo_ws ? (const void*)wob : (const void*)d_in[10],
              (const float*)d_in[11], out, 1.0f, 2, wo_ws ? 0 : 1 };
  po.p[1] = po.p[0]; po.p[2] = po.p[0];
  proj_kernel<<<dim3(64, 8, 1), 256, 0, stream>>>(po);
}